// Round 1
// baseline (8759.516 us; speedup 1.0000x reference)
//
#include <hip/hip_runtime.h>
#include <hip/hip_bf16.h>

// BiGRU: S=512, B=64, I=1024, H=512, bidirectional.
// Plan: (1) cast x, Wx to bf16; (2) one big MFMA GEMM xg = x@Wx for both dirs
// (M=32768,K=1024,N=3072, bf16 out); (3) persistent recurrence kernel: 64 blocks
// (2 dirs x 32 column-slices), Wh slices in LDS (swizzled), h/rh via global bf16,
// flat-flag device-scope barriers (2 per step).

typedef __attribute__((ext_vector_type(8))) short short8;   // 8 x bf16 (4 VGPRs)
typedef __attribute__((ext_vector_type(4))) float f32x4;    // MFMA acc

__device__ __forceinline__ unsigned short f2bf(float f) {
    unsigned u = __builtin_bit_cast(unsigned, f);
    u += 0x7FFFu + ((u >> 16) & 1u);           // RNE
    return (unsigned short)(u >> 16);
}
__device__ __forceinline__ float bf2f(unsigned short h) {
    unsigned u = ((unsigned)h) << 16;
    return __builtin_bit_cast(float, u);
}

// ---------------- converts ----------------

__global__ __launch_bounds__(256) void k_cvt_x(const float* __restrict__ x,
                                               unsigned short* __restrict__ xb) {
    size_t gid = (size_t)blockIdx.x * 256 + threadIdx.x;   // 4,194,304 threads x 8 elems
    f32x4 a = ((const f32x4*)x)[gid * 2];
    f32x4 b = ((const f32x4*)x)[gid * 2 + 1];
    short8 o;
    o[0] = (short)f2bf(a[0]); o[1] = (short)f2bf(a[1]);
    o[2] = (short)f2bf(a[2]); o[3] = (short)f2bf(a[3]);
    o[4] = (short)f2bf(b[0]); o[5] = (short)f2bf(b[1]);
    o[6] = (short)f2bf(b[2]); o[7] = (short)f2bf(b[3]);
    ((short8*)xb)[gid] = o;
}

// Wt[n][k] = Wx_d[g][k][h], n = d*1536 + g*512 + h  (B^T layout for GEMM)
__global__ __launch_bounds__(256) void k_cvt_w(const float* __restrict__ Wxf,
                                               const float* __restrict__ Wxb,
                                               unsigned short* __restrict__ wt) {
    int gid = blockIdx.x * 256 + threadIdx.x;   // 3072*128 = 393216
    int n = gid >> 7, kc = gid & 127;
    const float* src = (n < 1536) ? Wxf : Wxb;
    int nn = (n >= 1536) ? n - 1536 : n;
    int g = nn >> 9, h = nn & 511;
    short8 o;
#pragma unroll
    for (int j = 0; j < 8; ++j)
        o[j] = (short)f2bf(src[(size_t)(g * 1024 + kc * 8 + j) * 512 + h]);
    *(short8*)(wt + (size_t)n * 1024 + kc * 8) = o;
}

// whsl[d][w][g][c][k] = Wh_d[g][k][w*16+c]   (per-block contiguous 48KB slices)
__global__ __launch_bounds__(256) void k_cvt_whsl(const float* __restrict__ Whf,
                                                  const float* __restrict__ Whb,
                                                  unsigned short* __restrict__ o) {
    int gid = blockIdx.x * 256 + threadIdx.x;   // 196608
    int kc = gid & 63;
    int r = gid >> 6;          // 3072
    int c = r & 15; r >>= 4;   // 192
    int g = r % 3;  r /= 3;    // 64
    int w = r & 31, d = r >> 5;
    const float* src = d ? Whb : Whf;
    short8 v;
#pragma unroll
    for (int j = 0; j < 8; ++j)
        v[j] = (short)f2bf(src[(size_t)(g * 512 + kc * 8 + j) * 512 + w * 16 + c]);
    *(short8*)(o + ((size_t)((d * 32 + w) * 3 + g) * 16 + c) * 512 + kc * 8) = v;
}

// h_bf[d][b][k] = bf16(initial_state[b][d*512+k]); zero the barrier flags
__global__ __launch_bounds__(256) void k_init(const float* __restrict__ h0,
                                              unsigned short* __restrict__ hbf,
                                              int* __restrict__ flags) {
    int gid = blockIdx.x * 256 + threadIdx.x;   // 65536
    int b = gid >> 10, ch = gid & 1023;
    int d = ch >> 9, k = ch & 511;
    hbf[(size_t)(d * 64 + b) * 512 + k] = f2bf(h0[gid]);
    if (gid < 1024) flags[gid] = 0;
}

// ---------------- GEMM: xg[m][n] = sum_k x[m][k] * Wt[n][k], bf16 out ----------------

__global__ __launch_bounds__(256) void k_gemm(const unsigned short* __restrict__ A,
                                              const unsigned short* __restrict__ Bt,
                                              unsigned short* __restrict__ C) {
    __shared__ unsigned short Al[128 * 40];  // padded rows: 80B stride, ~2-way max conflicts
    __shared__ unsigned short Bl[128 * 40];
    const int n0 = blockIdx.x * 128;   // 24 n-tiles
    const int m0 = blockIdx.y * 128;   // 256 m-tiles
    const int t = threadIdx.x, wave = t >> 6, lane = t & 63;
    const int lg = lane >> 4, lr = lane & 15;
    const int wm = wave >> 1, wn = wave & 1;
    const int lrow = t >> 2, lkb = t & 3;

    f32x4 acc[4][4] = {};
    for (int kt = 0; kt < 32; ++kt) {
        const int k0 = kt * 32;
#pragma unroll
        for (int p = 0; p < 2; ++p) {
            int row = lrow + p * 64;
            *(short8*)(Al + row * 40 + lkb * 8) =
                *(const short8*)(A + (size_t)(m0 + row) * 1024 + k0 + lkb * 8);
            *(short8*)(Bl + row * 40 + lkb * 8) =
                *(const short8*)(Bt + (size_t)(n0 + row) * 1024 + k0 + lkb * 8);
        }
        __syncthreads();
        short8 af[4], bfr[4];
#pragma unroll
        for (int mi = 0; mi < 4; ++mi)
            af[mi] = *(const short8*)(Al + (wm * 64 + mi * 16 + lr) * 40 + lg * 8);
#pragma unroll
        for (int ni = 0; ni < 4; ++ni)
            bfr[ni] = *(const short8*)(Bl + (wn * 64 + ni * 16 + lr) * 40 + lg * 8);
#pragma unroll
        for (int mi = 0; mi < 4; ++mi)
#pragma unroll
            for (int ni = 0; ni < 4; ++ni)
                acc[mi][ni] = __builtin_amdgcn_mfma_f32_16x16x32_bf16(af[mi], bfr[ni],
                                                                      acc[mi][ni], 0, 0, 0);
        __syncthreads();
    }
#pragma unroll
    for (int mi = 0; mi < 4; ++mi)
#pragma unroll
        for (int ni = 0; ni < 4; ++ni) {
            int m = m0 + wm * 64 + mi * 16 + lg * 4;
            int n = n0 + wn * 64 + ni * 16 + lr;
#pragma unroll
            for (int jj = 0; jj < 4; ++jj)
                C[(size_t)(m + jj) * 3072 + n] = f2bf(acc[mi][ni][jj]);
        }
}

// ---------------- persistent recurrence ----------------
// 64 blocks: d = blk>>5 (direction), w = blk&31 (16-column slice per gate).
// Per step: stage h (bf16, swizzled) -> MFMA r,u preacts -> sigmoid, rh -> global
// -> barrier -> stage rh -> MFMA c preact -> tanh, blend -> h/out -> barrier.

__global__ __launch_bounds__(256) void k_rec(const unsigned short* __restrict__ xg,
                                             const unsigned short* __restrict__ whsl,
                                             const float* __restrict__ h0,
                                             const float* __restrict__ b_f,
                                             const float* __restrict__ b_b,
                                             unsigned short* __restrict__ h_bf,
                                             unsigned short* __restrict__ rh_bf,
                                             int* __restrict__ flags,
                                             float* __restrict__ out) {
    __shared__ unsigned short Wl[3 * 16 * 512];   // 48KB [g][c][k], XOR-swizzled
    __shared__ unsigned short Ast[64 * 512];      // 64KB [b][k], XOR-swizzled
    __shared__ float xgs[3 * 64 * 16];            // 12KB [g][b][c]

    const int blk = blockIdx.x;
    const int d = blk >> 5, w = blk & 31;
    const int t = threadIdx.x;
    const int wave = t >> 6, lane = t & 63;
    const int lg = lane >> 4, lr = lane & 15;

    // load weight slice into LDS (swizzle: byte ^= ((byte>>10)&7)<<4)
    {
        const char* wsrc = (const char*)(whsl + (size_t)(d * 32 + w) * (3 * 16 * 512));
#pragma unroll
        for (int i = 0; i < 12; ++i) {
            int byte = (t + i * 256) << 4;
            int swz = byte ^ (((byte >> 10) & 7) << 4);
            *(short8*)((char*)Wl + swz) = *(const short8*)(wsrc + byte);
        }
    }
    const float* bias = d ? b_b : b_f;
    const int col = w * 16 + lr;
    const float b0 = bias[col], b1 = bias[512 + col], b2 = bias[1024 + col];

    float h_own[4];
#pragma unroll
    for (int jj = 0; jj < 4; ++jj)
        h_own[jj] = h0[(size_t)(wave * 16 + lg * 4 + jj) * 1024 + d * 512 + col];

    const int arow = wave * 16 + lr;
    const int aswz = (arow & 7) << 4;
    const int cswz = (lr & 7) << 4;

    int bar = 0;
    for (int step = 0; step < 512; ++step) {
        const int s = d ? (511 - step) : step;

        // stage xg[s] slice (3 gates x 64 x 16) as fp32
        {
            const unsigned short* base = xg + (size_t)s * 64 * 3072 + d * 1536 + w * 16;
            for (int ch = t; ch < 384; ch += 256) {
                int e0 = ch << 3;
                int g = e0 >> 10, b = (e0 >> 4) & 63, hf = (e0 >> 3) & 1;
                short8 v = *(const short8*)(base + (size_t)b * 3072 + g * 512 + hf * 8);
                float* dst = xgs + g * 1024 + b * 16 + hf * 8;
#pragma unroll
                for (int j = 0; j < 8; ++j) dst[j] = bf2f((unsigned short)v[j]);
            }
        }
        // stage A = h (swizzled)
        {
            const short8* src = (const short8*)(h_bf + (size_t)d * 64 * 512);
#pragma unroll
            for (int i = 0; i < 16; ++i) {
                int byte = (t + i * 256) << 4;
                int swz = byte ^ (((byte >> 10) & 7) << 4);
                *(short8*)((char*)Ast + swz) = src[t + i * 256];
            }
        }
        __syncthreads();

        // phase 1: r,u preacts (each wave: one 16-row M-tile, 16 cols per gate)
        f32x4 accR = {0.f, 0.f, 0.f, 0.f}, accU = {0.f, 0.f, 0.f, 0.f};
#pragma unroll
        for (int ks = 0; ks < 16; ++ks) {
            int koff = (ks * 32 + lg * 8) * 2;
            short8 a  = *(const short8*)((const char*)Ast + (((arow << 10) + koff) ^ aswz));
            short8 w0 = *(const short8*)((const char*)Wl + (((lr << 10) + koff) ^ cswz));
            short8 w1 = *(const short8*)((const char*)Wl + ((16384 + (lr << 10) + koff) ^ cswz));
            accR = __builtin_amdgcn_mfma_f32_16x16x32_bf16(a, w0, accR, 0, 0, 0);
            accU = __builtin_amdgcn_mfma_f32_16x16x32_bf16(a, w1, accU, 0, 0, 0);
        }
        float u_[4];
#pragma unroll
        for (int jj = 0; jj < 4; ++jj) {
            int b = wave * 16 + lg * 4 + jj;
            float pr = accR[jj] + xgs[b * 16 + lr] + b0;
            float pu = accU[jj] + xgs[1024 + b * 16 + lr] + b1;
            float r = 1.f / (1.f + __expf(-pr));
            u_[jj] = 1.f / (1.f + __expf(-pu));
            rh_bf[(size_t)(d * 64 + b) * 512 + col] = f2bf(r * h_own[jj]);
        }

        // barrier 1 (rh ready)
        ++bar;
        __syncthreads();
        if (t == 0)
            __hip_atomic_store(flags + blk * 16, bar, __ATOMIC_RELEASE, __HIP_MEMORY_SCOPE_AGENT);
        if (t < 64) {
            while (__hip_atomic_load(flags + t * 16, __ATOMIC_ACQUIRE, __HIP_MEMORY_SCOPE_AGENT) < bar)
                __builtin_amdgcn_s_sleep(2);
        }
        __syncthreads();

        // stage A = rh (swizzled)
        {
            const short8* src = (const short8*)(rh_bf + (size_t)d * 64 * 512);
#pragma unroll
            for (int i = 0; i < 16; ++i) {
                int byte = (t + i * 256) << 4;
                int swz = byte ^ (((byte >> 10) & 7) << 4);
                *(short8*)((char*)Ast + swz) = src[t + i * 256];
            }
        }
        __syncthreads();

        // phase 2: c preact
        f32x4 accC = {0.f, 0.f, 0.f, 0.f};
#pragma unroll
        for (int ks = 0; ks < 16; ++ks) {
            int koff = (ks * 32 + lg * 8) * 2;
            short8 a  = *(const short8*)((const char*)Ast + (((arow << 10) + koff) ^ aswz));
            short8 w2 = *(const short8*)((const char*)Wl + ((32768 + (lr << 10) + koff) ^ cswz));
            accC = __builtin_amdgcn_mfma_f32_16x16x32_bf16(a, w2, accC, 0, 0, 0);
        }
#pragma unroll
        for (int jj = 0; jj < 4; ++jj) {
            int b = wave * 16 + lg * 4 + jj;
            float pc = accC[jj] + xgs[2048 + b * 16 + lr] + b2;
            float e = __expf(-2.f * pc);
            float c = 2.f / (1.f + e) - 1.f;                 // tanh
            float hn = u_[jj] * h_own[jj] + (1.f - u_[jj]) * c;
            h_own[jj] = hn;
            out[((size_t)s * 64 + b) * 1024 + d * 512 + col] = hn;
            h_bf[(size_t)(d * 64 + b) * 512 + col] = f2bf(hn);
            if (step == 511)
                out[(size_t)33554432 + (size_t)b * 1024 + d * 512 + col] = hn;
        }

        // barrier 2 (h ready)
        ++bar;
        __syncthreads();
        if (t == 0)
            __hip_atomic_store(flags + blk * 16, bar, __ATOMIC_RELEASE, __HIP_MEMORY_SCOPE_AGENT);
        if (t < 64) {
            while (__hip_atomic_load(flags + t * 16, __ATOMIC_ACQUIRE, __HIP_MEMORY_SCOPE_AGENT) < bar)
                __builtin_amdgcn_s_sleep(2);
        }
        __syncthreads();
    }
}

// ---------------- launcher ----------------

extern "C" void kernel_launch(void* const* d_in, const int* in_sizes, int n_in,
                              void* d_out, int out_size, void* d_ws, size_t ws_size,
                              hipStream_t stream) {
    const float* x   = (const float*)d_in[0];
    const float* h0  = (const float*)d_in[1];
    const float* Wxf = (const float*)d_in[2];
    const float* Whf = (const float*)d_in[3];
    const float* bf_ = (const float*)d_in[4];
    const float* Wxb = (const float*)d_in[5];
    const float* Whb = (const float*)d_in[6];
    const float* bb_ = (const float*)d_in[7];
    float* out = (float*)d_out;

    char* ws = (char*)d_ws;
    size_t off = 0;
    auto take = [&](size_t bytes) {
        char* p = ws + off;
        off += (bytes + 255) & ~(size_t)255;
        return p;
    };
    unsigned short* xb   = (unsigned short*)take((size_t)33554432 * 2);          // x bf16
    unsigned short* wt   = (unsigned short*)take((size_t)3072 * 1024 * 2);       // Wx^T bf16
    unsigned short* xg   = (unsigned short*)take((size_t)32768 * 3072 * 2);      // gates bf16
    unsigned short* whsl = (unsigned short*)take((size_t)2 * 32 * 3 * 16 * 512 * 2); // Wh slices
    unsigned short* hbf  = (unsigned short*)take((size_t)2 * 64 * 512 * 2);      // h bf16
    unsigned short* rhbf = (unsigned short*)take((size_t)2 * 64 * 512 * 2);      // r*h bf16
    int* flags           = (int*)take((size_t)64 * 16 * 4);                      // barrier flags

    if (off > ws_size) return;  // workspace too small -> clean validation failure

    hipLaunchKernelGGL(k_cvt_x,    dim3(16384),   dim3(256), 0, stream, x, xb);
    hipLaunchKernelGGL(k_cvt_w,    dim3(1536),    dim3(256), 0, stream, Wxf, Wxb, wt);
    hipLaunchKernelGGL(k_cvt_whsl, dim3(768),     dim3(256), 0, stream, Whf, Whb, whsl);
    hipLaunchKernelGGL(k_init,     dim3(256),     dim3(256), 0, stream, h0, hbf, flags);
    hipLaunchKernelGGL(k_gemm,     dim3(24, 256), dim3(256), 0, stream, xb, wt, xg);
    hipLaunchKernelGGL(k_rec,      dim3(64),      dim3(256), 0, stream, xg, whsl, h0,
                       bf_, bb_, hbf, rhbf, flags, out);
}

// Round 3
// 8062.373 us; speedup vs baseline: 1.0865x; 1.0865x over previous
//
#include <hip/hip_runtime.h>
#include <hip/hip_bf16.h>

// BiGRU: S=512, B=64, I=1024, H=512, bidirectional.
// (1) cast x, Wx to bf16; (2) MFMA GEMM xg = x@Wx for both dirs (M=32768,K=1024,
// N=3072, bf16 out); (3) persistent recurrence: 64 blocks (2 dirs x 32 col-slices),
// Wh slices in LDS (swizzled), h/rh via global bf16, per-direction flat-flag
// barriers with relaxed polling + single acquire/release fences
// (__builtin_amdgcn_fence; __hip_atomic_fence does not exist on this ROCm).

typedef __attribute__((ext_vector_type(8))) short short8;   // 8 x bf16 (4 VGPRs)
typedef __attribute__((ext_vector_type(4))) float f32x4;    // MFMA acc

__device__ __forceinline__ unsigned short f2bf(float f) {
    unsigned u = __builtin_bit_cast(unsigned, f);
    u += 0x7FFFu + ((u >> 16) & 1u);           // RNE
    return (unsigned short)(u >> 16);
}
__device__ __forceinline__ float bf2f(unsigned short h) {
    unsigned u = ((unsigned)h) << 16;
    return __builtin_bit_cast(float, u);
}

// ---------------- converts ----------------

__global__ __launch_bounds__(256) void k_cvt_x(const float* __restrict__ x,
                                               unsigned short* __restrict__ xb) {
    size_t gid = (size_t)blockIdx.x * 256 + threadIdx.x;   // 4,194,304 threads x 8 elems
    f32x4 a = ((const f32x4*)x)[gid * 2];
    f32x4 b = ((const f32x4*)x)[gid * 2 + 1];
    short8 o;
    o[0] = (short)f2bf(a[0]); o[1] = (short)f2bf(a[1]);
    o[2] = (short)f2bf(a[2]); o[3] = (short)f2bf(a[3]);
    o[4] = (short)f2bf(b[0]); o[5] = (short)f2bf(b[1]);
    o[6] = (short)f2bf(b[2]); o[7] = (short)f2bf(b[3]);
    ((short8*)xb)[gid] = o;
}

// Wt[n][k] = Wx_d[g][k][h], n = d*1536 + g*512 + h  (B^T layout for GEMM)
__global__ __launch_bounds__(256) void k_cvt_w(const float* __restrict__ Wxf,
                                               const float* __restrict__ Wxb,
                                               unsigned short* __restrict__ wt) {
    int gid = blockIdx.x * 256 + threadIdx.x;   // 393216
    int n = gid >> 7, kc = gid & 127;
    const float* src = (n < 1536) ? Wxf : Wxb;
    int nn = (n >= 1536) ? n - 1536 : n;
    int g = nn >> 9, h = nn & 511;
    short8 o;
#pragma unroll
    for (int j = 0; j < 8; ++j)
        o[j] = (short)f2bf(src[(size_t)(g * 1024 + kc * 8 + j) * 512 + h]);
    *(short8*)(wt + (size_t)n * 1024 + kc * 8) = o;
}

// whsl[d][w][g][c][k] = Wh_d[g][k][w*16+c]   (per-block contiguous 48KB slices)
__global__ __launch_bounds__(256) void k_cvt_whsl(const float* __restrict__ Whf,
                                                  const float* __restrict__ Whb,
                                                  unsigned short* __restrict__ o) {
    int gid = blockIdx.x * 256 + threadIdx.x;   // 196608
    int kc = gid & 63;
    int r = gid >> 6;          // 3072
    int c = r & 15; r >>= 4;   // 192
    int g = r % 3;  r /= 3;    // 64
    int w = r & 31, d = r >> 5;
    const float* src = d ? Whb : Whf;
    short8 v;
#pragma unroll
    for (int j = 0; j < 8; ++j)
        v[j] = (short)f2bf(src[(size_t)(g * 512 + kc * 8 + j) * 512 + w * 16 + c]);
    *(short8*)(o + ((size_t)((d * 32 + w) * 3 + g) * 16 + c) * 512 + kc * 8) = v;
}

// h_bf[d][b][k] = bf16(initial_state[b][d*512+k]); zero the barrier flags
__global__ __launch_bounds__(256) void k_init(const float* __restrict__ h0,
                                              unsigned short* __restrict__ hbf,
                                              int* __restrict__ flags) {
    int gid = blockIdx.x * 256 + threadIdx.x;   // 65536
    int b = gid >> 10, ch = gid & 1023;
    int d = ch >> 9, k = ch & 511;
    hbf[(size_t)(d * 64 + b) * 512 + k] = f2bf(h0[gid]);
    if (gid < 1024) flags[gid] = 0;
}

// ---------------- GEMM: xg[m][n] = sum_k x[m][k] * Wt[n][k], bf16 out ----------------

__global__ __launch_bounds__(256) void k_gemm(const unsigned short* __restrict__ A,
                                              const unsigned short* __restrict__ Bt,
                                              unsigned short* __restrict__ C) {
    __shared__ unsigned short Al[128 * 40];
    __shared__ unsigned short Bl[128 * 40];
    const int n0 = blockIdx.x * 128;   // 24 n-tiles
    const int m0 = blockIdx.y * 128;   // 256 m-tiles
    const int t = threadIdx.x, wave = t >> 6, lane = t & 63;
    const int lg = lane >> 4, lr = lane & 15;
    const int wm = wave >> 1, wn = wave & 1;
    const int lrow = t >> 2, lkb = t & 3;

    f32x4 acc[4][4] = {};
    for (int kt = 0; kt < 32; ++kt) {
        const int k0 = kt * 32;
#pragma unroll
        for (int p = 0; p < 2; ++p) {
            int row = lrow + p * 64;
            *(short8*)(Al + row * 40 + lkb * 8) =
                *(const short8*)(A + (size_t)(m0 + row) * 1024 + k0 + lkb * 8);
            *(short8*)(Bl + row * 40 + lkb * 8) =
                *(const short8*)(Bt + (size_t)(n0 + row) * 1024 + k0 + lkb * 8);
        }
        __syncthreads();
        short8 af[4], bfr[4];
#pragma unroll
        for (int mi = 0; mi < 4; ++mi)
            af[mi] = *(const short8*)(Al + (wm * 64 + mi * 16 + lr) * 40 + lg * 8);
#pragma unroll
        for (int ni = 0; ni < 4; ++ni)
            bfr[ni] = *(const short8*)(Bl + (wn * 64 + ni * 16 + lr) * 40 + lg * 8);
#pragma unroll
        for (int mi = 0; mi < 4; ++mi)
#pragma unroll
            for (int ni = 0; ni < 4; ++ni)
                acc[mi][ni] = __builtin_amdgcn_mfma_f32_16x16x32_bf16(af[mi], bfr[ni],
                                                                      acc[mi][ni], 0, 0, 0);
        __syncthreads();
    }
#pragma unroll
    for (int mi = 0; mi < 4; ++mi)
#pragma unroll
        for (int ni = 0; ni < 4; ++ni) {
            int m = m0 + wm * 64 + mi * 16 + lg * 4;
            int n = n0 + wn * 64 + ni * 16 + lr;
#pragma unroll
            for (int jj = 0; jj < 4; ++jj)
                C[(size_t)(m + jj) * 3072 + n] = f2bf(acc[mi][ni][jj]);
        }
}

// ---------------- persistent recurrence ----------------
// Per step: stage h (bf16, swizzled) -> MFMA r,u preacts -> sigmoid, rh -> global
// -> dir-barrier (xg prefetch under it) -> stage rh -> MFMA c preact -> tanh,
// blend -> h/out -> dir-barrier.
// Barrier discipline: syncthreads (drains vmcnt) -> t0 {release fence (wbl2) +
// relaxed flag store} -> wave0 relaxed-polls 32 dir flags -> wave0 acquire fence
// (buffer_inv; L1 is CU-shared, L2 XCD-shared, so one wave covers the block)
// -> syncthreads.

__global__ __launch_bounds__(256) void k_rec(const unsigned short* __restrict__ xg,
                                             const unsigned short* __restrict__ whsl,
                                             const float* __restrict__ h0,
                                             const float* __restrict__ b_f,
                                             const float* __restrict__ b_b,
                                             unsigned short* __restrict__ h_bf,
                                             unsigned short* __restrict__ rh_bf,
                                             int* flags,
                                             float* __restrict__ out) {
    __shared__ unsigned short Wl[3 * 16 * 512];   // 48KB [g][c][k], XOR-swizzled
    __shared__ unsigned short Ast[64 * 512];      // 64KB [b][k], XOR-swizzled
    __shared__ float xgs[2][3 * 64 * 16];         // 2 x 12KB [g][b][c], double-buffered

    const int blk = blockIdx.x;
    const int d = blk >> 5, w = blk & 31;
    const int t = threadIdx.x;
    const int wave = t >> 6, lane = t & 63;
    const int lg = lane >> 4, lr = lane & 15;

    // load weight slice into LDS (swizzle: byte ^= ((byte>>10)&7)<<4)
    {
        const char* wsrc = (const char*)(whsl + (size_t)(d * 32 + w) * (3 * 16 * 512));
#pragma unroll
        for (int i = 0; i < 12; ++i) {
            int byte = (t + i * 256) << 4;
            int swz = byte ^ (((byte >> 10) & 7) << 4);
            *(short8*)((char*)Wl + swz) = *(const short8*)(wsrc + byte);
        }
    }
    const float* bias = d ? b_b : b_f;
    const int col = w * 16 + lr;
    const float b0 = bias[col], b1 = bias[512 + col], b2 = bias[1024 + col];

    float h_own[4];
#pragma unroll
    for (int jj = 0; jj < 4; ++jj)
        h_own[jj] = h0[(size_t)(wave * 16 + lg * 4 + jj) * 1024 + d * 512 + col];

    const int arow = wave * 16 + lr;
    const int aswz = (arow & 7) << 4;
    const int cswz = (lr & 7) << 4;

    auto stage_xgs = [&](int buf, int ss) {
        const unsigned short* base = xg + (size_t)ss * (64 * 3072) + d * 1536 + w * 16;
        for (int ch = t; ch < 384; ch += 256) {
            int e0 = ch << 3;
            int g = e0 >> 10, b = (e0 >> 4) & 63, hf = (e0 >> 3) & 1;
            short8 v = *(const short8*)(base + (size_t)b * 3072 + g * 512 + hf * 8);
            float* dst = &xgs[buf][g * 1024 + b * 16 + hf * 8];
#pragma unroll
            for (int j = 0; j < 8; ++j) dst[j] = bf2f((unsigned short)v[j]);
        }
    };

    // prologue: stage xg for the first step
    stage_xgs(0, d ? 511 : 0);

    int bar = 0, cur = 0;
    for (int step = 0; step < 512; ++step) {
        const int s = d ? (511 - step) : step;

        // stage A = h (swizzled)
        {
            const short8* src = (const short8*)(h_bf + (size_t)d * 64 * 512);
#pragma unroll
            for (int i = 0; i < 16; ++i) {
                int byte = (t + i * 256) << 4;
                int swz = byte ^ (((byte >> 10) & 7) << 4);
                *(short8*)((char*)Ast + swz) = src[t + i * 256];
            }
        }
        __syncthreads();

        // phase 1: r,u preacts (each wave: one 16-row M-tile, 16 cols per gate)
        f32x4 accR = {0.f, 0.f, 0.f, 0.f}, accU = {0.f, 0.f, 0.f, 0.f};
#pragma unroll
        for (int ks = 0; ks < 16; ++ks) {
            int koff = (ks * 32 + lg * 8) * 2;
            short8 a  = *(const short8*)((const char*)Ast + (((arow << 10) + koff) ^ aswz));
            short8 w0 = *(const short8*)((const char*)Wl + (((lr << 10) + koff) ^ cswz));
            short8 w1 = *(const short8*)((const char*)Wl + ((16384 + (lr << 10) + koff) ^ cswz));
            accR = __builtin_amdgcn_mfma_f32_16x16x32_bf16(a, w0, accR, 0, 0, 0);
            accU = __builtin_amdgcn_mfma_f32_16x16x32_bf16(a, w1, accU, 0, 0, 0);
        }
        float u_[4];
        const float* xc = xgs[cur];
#pragma unroll
        for (int jj = 0; jj < 4; ++jj) {
            int b = wave * 16 + lg * 4 + jj;
            float pr = accR[jj] + xc[b * 16 + lr] + b0;
            float pu = accU[jj] + xc[1024 + b * 16 + lr] + b1;
            float r = 1.f / (1.f + __expf(-pr));
            u_[jj] = 1.f / (1.f + __expf(-pu));
            rh_bf[(size_t)(d * 64 + b) * 512 + col] = f2bf(r * h_own[jj]);
        }

        // barrier 1 (rh ready), xg prefetch hidden under it
        ++bar;
        __syncthreads();
        if (t == 0) {
            __builtin_amdgcn_fence(__ATOMIC_RELEASE, "agent");
            __hip_atomic_store(&flags[blk], bar, __ATOMIC_RELAXED, __HIP_MEMORY_SCOPE_AGENT);
        }
        if (step + 1 < 512) stage_xgs(cur ^ 1, d ? (510 - step) : (step + 1));
        if (t < 64) {
            if (t < 32) {
                while (__hip_atomic_load(&flags[d * 32 + t], __ATOMIC_RELAXED,
                                         __HIP_MEMORY_SCOPE_AGENT) < bar)
                    __builtin_amdgcn_s_sleep(1);
            }
            __builtin_amdgcn_fence(__ATOMIC_ACQUIRE, "agent");
        }
        __syncthreads();

        // stage A = rh (swizzled)
        {
            const short8* src = (const short8*)(rh_bf + (size_t)d * 64 * 512);
#pragma unroll
            for (int i = 0; i < 16; ++i) {
                int byte = (t + i * 256) << 4;
                int swz = byte ^ (((byte >> 10) & 7) << 4);
                *(short8*)((char*)Ast + swz) = src[t + i * 256];
            }
        }
        __syncthreads();

        // phase 2: c preact
        f32x4 accC = {0.f, 0.f, 0.f, 0.f};
#pragma unroll
        for (int ks = 0; ks < 16; ++ks) {
            int koff = (ks * 32 + lg * 8) * 2;
            short8 a  = *(const short8*)((const char*)Ast + (((arow << 10) + koff) ^ aswz));
            short8 w2 = *(const short8*)((const char*)Wl + ((32768 + (lr << 10) + koff) ^ cswz));
            accC = __builtin_amdgcn_mfma_f32_16x16x32_bf16(a, w2, accC, 0, 0, 0);
        }
#pragma unroll
        for (int jj = 0; jj < 4; ++jj) {
            int b = wave * 16 + lg * 4 + jj;
            float pc = accC[jj] + xc[2048 + b * 16 + lr] + b2;
            float e = __expf(-2.f * pc);
            float c = 2.f / (1.f + e) - 1.f;                 // tanh
            float hn = u_[jj] * h_own[jj] + (1.f - u_[jj]) * c;
            h_own[jj] = hn;
            __builtin_nontemporal_store(hn, &out[((size_t)s * 64 + b) * 1024 + d * 512 + col]);
            h_bf[(size_t)(d * 64 + b) * 512 + col] = f2bf(hn);
            if (step == 511)
                __builtin_nontemporal_store(
                    hn, &out[(size_t)33554432 + (size_t)b * 1024 + d * 512 + col]);
        }

        // barrier 2 (h ready) — skip after the last step
        if (step == 511) break;
        ++bar;
        __syncthreads();
        if (t == 0) {
            __builtin_amdgcn_fence(__ATOMIC_RELEASE, "agent");
            __hip_atomic_store(&flags[blk], bar, __ATOMIC_RELAXED, __HIP_MEMORY_SCOPE_AGENT);
        }
        if (t < 64) {
            if (t < 32) {
                while (__hip_atomic_load(&flags[d * 32 + t], __ATOMIC_RELAXED,
                                         __HIP_MEMORY_SCOPE_AGENT) < bar)
                    __builtin_amdgcn_s_sleep(1);
            }
            __builtin_amdgcn_fence(__ATOMIC_ACQUIRE, "agent");
        }
        __syncthreads();
        cur ^= 1;
    }
}

// ---------------- launcher ----------------

extern "C" void kernel_launch(void* const* d_in, const int* in_sizes, int n_in,
                              void* d_out, int out_size, void* d_ws, size_t ws_size,
                              hipStream_t stream) {
    const float* x   = (const float*)d_in[0];
    const float* h0  = (const float*)d_in[1];
    const float* Wxf = (const float*)d_in[2];
    const float* Whf = (const float*)d_in[3];
    const float* bf_ = (const float*)d_in[4];
    const float* Wxb = (const float*)d_in[5];
    const float* Whb = (const float*)d_in[6];
    const float* bb_ = (const float*)d_in[7];
    float* out = (float*)d_out;

    char* ws = (char*)d_ws;
    size_t off = 0;
    auto take = [&](size_t bytes) {
        char* p = ws + off;
        off += (bytes + 255) & ~(size_t)255;
        return p;
    };
    unsigned short* xb   = (unsigned short*)take((size_t)33554432 * 2);          // x bf16
    unsigned short* wt   = (unsigned short*)take((size_t)3072 * 1024 * 2);       // Wx^T bf16
    unsigned short* xg   = (unsigned short*)take((size_t)32768 * 3072 * 2);      // gates bf16
    unsigned short* whsl = (unsigned short*)take((size_t)2 * 32 * 3 * 16 * 512 * 2); // Wh slices
    unsigned short* hbf  = (unsigned short*)take((size_t)2 * 64 * 512 * 2);      // h bf16
    unsigned short* rhbf = (unsigned short*)take((size_t)2 * 64 * 512 * 2);      // r*h bf16
    int* flags           = (int*)take((size_t)1024 * 4);                         // barrier flags

    if (off > ws_size) return;  // workspace too small -> clean validation failure

    hipLaunchKernelGGL(k_cvt_x,    dim3(16384),   dim3(256), 0, stream, x, xb);
    hipLaunchKernelGGL(k_cvt_w,    dim3(1536),    dim3(256), 0, stream, Wxf, Wxb, wt);
    hipLaunchKernelGGL(k_cvt_whsl, dim3(768),     dim3(256), 0, stream, Whf, Whb, whsl);
    hipLaunchKernelGGL(k_init,     dim3(256),     dim3(256), 0, stream, h0, hbf, flags);
    hipLaunchKernelGGL(k_gemm,     dim3(24, 256), dim3(256), 0, stream, xb, wt, xg);
    hipLaunchKernelGGL(k_rec,      dim3(64),      dim3(256), 0, stream, xg, whsl, h0,
                       bf_, bb_, hbf, rhbf, flags, out);
}

// Round 4
// 5618.736 us; speedup vs baseline: 1.5590x; 1.4349x over previous
//
#include <hip/hip_runtime.h>
#include <hip/hip_bf16.h>

// BiGRU: S=512, B=64, I=1024, H=512, bidirectional.
// (1) cast x, Wx to bf16; (2) MFMA GEMM xg = x@Wx for both dirs; (3) persistent
// recurrence: 64 blocks (2 dirs x 32 col-slices), Wh slices in LDS, all
// cross-block h/rh traffic via agent-scope RELAXED atomics (sc1, cache-bypass:
// NO buffer_wbl2/buffer_inv in the loop). MFMA operands swapped (preact^T =
// Wh^T . h^T) so each thread owns 4 consecutive columns -> 8B packed atomic
// publishes, float4 out stores, and register-direct B-fragment loads.

typedef __attribute__((ext_vector_type(8))) short short8;   // 8 x bf16
typedef __attribute__((ext_vector_type(4))) float f32x4;
typedef __attribute__((ext_vector_type(2))) unsigned long long ulongx2;

__device__ __forceinline__ unsigned short f2bf(float f) {
    unsigned u = __builtin_bit_cast(unsigned, f);
    u += 0x7FFFu + ((u >> 16) & 1u);           // RNE
    return (unsigned short)(u >> 16);
}
__device__ __forceinline__ float bf2f(unsigned short h) {
    unsigned u = ((unsigned)h) << 16;
    return __builtin_bit_cast(float, u);
}

// ---------------- converts ----------------

__global__ __launch_bounds__(256) void k_cvt_x(const float* __restrict__ x,
                                               unsigned short* __restrict__ xb) {
    size_t gid = (size_t)blockIdx.x * 256 + threadIdx.x;
    f32x4 a = ((const f32x4*)x)[gid * 2];
    f32x4 b = ((const f32x4*)x)[gid * 2 + 1];
    short8 o;
    o[0] = (short)f2bf(a[0]); o[1] = (short)f2bf(a[1]);
    o[2] = (short)f2bf(a[2]); o[3] = (short)f2bf(a[3]);
    o[4] = (short)f2bf(b[0]); o[5] = (short)f2bf(b[1]);
    o[6] = (short)f2bf(b[2]); o[7] = (short)f2bf(b[3]);
    ((short8*)xb)[gid] = o;
}

__global__ __launch_bounds__(256) void k_cvt_w(const float* __restrict__ Wxf,
                                               const float* __restrict__ Wxb,
                                               unsigned short* __restrict__ wt) {
    int gid = blockIdx.x * 256 + threadIdx.x;   // 393216
    int n = gid >> 7, kc = gid & 127;
    const float* src = (n < 1536) ? Wxf : Wxb;
    int nn = (n >= 1536) ? n - 1536 : n;
    int g = nn >> 9, h = nn & 511;
    short8 o;
#pragma unroll
    for (int j = 0; j < 8; ++j)
        o[j] = (short)f2bf(src[(size_t)(g * 1024 + kc * 8 + j) * 512 + h]);
    *(short8*)(wt + (size_t)n * 1024 + kc * 8) = o;
}

// whsl[d][w][g][c][k] = Wh_d[g][k][w*16+c]
__global__ __launch_bounds__(256) void k_cvt_whsl(const float* __restrict__ Whf,
                                                  const float* __restrict__ Whb,
                                                  unsigned short* __restrict__ o) {
    int gid = blockIdx.x * 256 + threadIdx.x;   // 196608
    int kc = gid & 63;
    int r = gid >> 6;
    int c = r & 15; r >>= 4;
    int g = r % 3;  r /= 3;
    int w = r & 31, d = r >> 5;
    const float* src = d ? Whb : Whf;
    short8 v;
#pragma unroll
    for (int j = 0; j < 8; ++j)
        v[j] = (short)f2bf(src[(size_t)(g * 512 + kc * 8 + j) * 512 + w * 16 + c]);
    *(short8*)(o + ((size_t)((d * 32 + w) * 3 + g) * 16 + c) * 512 + kc * 8) = v;
}

__global__ __launch_bounds__(256) void k_init(const float* __restrict__ h0,
                                              unsigned short* __restrict__ hbf,
                                              int* __restrict__ flags) {
    int gid = blockIdx.x * 256 + threadIdx.x;   // 65536
    int b = gid >> 10, ch = gid & 1023;
    int d = ch >> 9, k = ch & 511;
    hbf[(size_t)(d * 64 + b) * 512 + k] = f2bf(h0[gid]);
    if (gid < 1024) flags[gid] = 0;
}

// ---------------- GEMM: xg[m][n] = sum_k x[m][k] * Wt[n][k] ----------------

__global__ __launch_bounds__(256) void k_gemm(const unsigned short* __restrict__ A,
                                              const unsigned short* __restrict__ Bt,
                                              unsigned short* __restrict__ C) {
    __shared__ unsigned short Al[128 * 40];
    __shared__ unsigned short Bl[128 * 40];
    const int n0 = blockIdx.x * 128;
    const int m0 = blockIdx.y * 128;
    const int t = threadIdx.x, wave = t >> 6, lane = t & 63;
    const int lg = lane >> 4, lr = lane & 15;
    const int wm = wave >> 1, wn = wave & 1;
    const int lrow = t >> 2, lkb = t & 3;

    f32x4 acc[4][4] = {};
    for (int kt = 0; kt < 32; ++kt) {
        const int k0 = kt * 32;
#pragma unroll
        for (int p = 0; p < 2; ++p) {
            int row = lrow + p * 64;
            *(short8*)(Al + row * 40 + lkb * 8) =
                *(const short8*)(A + (size_t)(m0 + row) * 1024 + k0 + lkb * 8);
            *(short8*)(Bl + row * 40 + lkb * 8) =
                *(const short8*)(Bt + (size_t)(n0 + row) * 1024 + k0 + lkb * 8);
        }
        __syncthreads();
        short8 af[4], bfr[4];
#pragma unroll
        for (int mi = 0; mi < 4; ++mi)
            af[mi] = *(const short8*)(Al + (wm * 64 + mi * 16 + lr) * 40 + lg * 8);
#pragma unroll
        for (int ni = 0; ni < 4; ++ni)
            bfr[ni] = *(const short8*)(Bl + (wn * 64 + ni * 16 + lr) * 40 + lg * 8);
#pragma unroll
        for (int mi = 0; mi < 4; ++mi)
#pragma unroll
            for (int ni = 0; ni < 4; ++ni)
                acc[mi][ni] = __builtin_amdgcn_mfma_f32_16x16x32_bf16(af[mi], bfr[ni],
                                                                      acc[mi][ni], 0, 0, 0);
        __syncthreads();
    }
#pragma unroll
    for (int mi = 0; mi < 4; ++mi)
#pragma unroll
        for (int ni = 0; ni < 4; ++ni) {
            int m = m0 + wm * 64 + mi * 16 + lg * 4;
            int n = n0 + wn * 64 + ni * 16 + lr;
#pragma unroll
            for (int jj = 0; jj < 4; ++jj)
                C[(size_t)(m + jj) * 3072 + n] = f2bf(acc[mi][ni][jj]);
        }
}

// ---------------- persistent recurrence ----------------
// Thread (wave,lg,lr) owns batch row b = wave*16+lr, cols cc0 = w*16+lg*4 .. +3.
// Phase 1: accR/U^T = mfma(Wl_frag, h_frag); sigmoid; publish packed rh (8B atomic).
// Barrier (no cache ops). Phase 2: accC^T = mfma(Wl2, rh_frag); tanh; blend;
// publish h + out float4. Barrier.

__global__ __launch_bounds__(256) void k_rec(const unsigned short* __restrict__ xg,
                                             const unsigned short* __restrict__ whsl,
                                             const float* __restrict__ h0,
                                             const float* __restrict__ b_f,
                                             const float* __restrict__ b_b,
                                             unsigned long long* h64,
                                             unsigned long long* rh64,
                                             int* flags,
                                             float* __restrict__ out) {
    __shared__ unsigned short Wl[3 * 16 * 512];   // 48KB [g][c][k], XOR-swizzled
    __shared__ unsigned short xgs[2][3 * 64 * 16];// 2 x 6KB [g][b][c] bf16

    const int blk = blockIdx.x;
    const int d = blk >> 5, w = blk & 31;
    const int t = threadIdx.x;
    const int wave = t >> 6, lane = t & 63;
    const int lg = lane >> 4, lr = lane & 15;

    // load weight slice into LDS (swizzle: byte ^= ((byte>>10)&7)<<4)
    {
        const char* wsrc = (const char*)(whsl + (size_t)(d * 32 + w) * (3 * 16 * 512));
#pragma unroll
        for (int i = 0; i < 12; ++i) {
            int byte = (t + i * 256) << 4;
            int swz = byte ^ (((byte >> 10) & 7) << 4);
            *(short8*)((char*)Wl + swz) = *(const short8*)(wsrc + byte);
        }
    }
    const float* bias = d ? b_b : b_f;
    const int cc0 = w * 16 + lg * 4;     // 4 consecutive owned columns
    const int b   = wave * 16 + lr;      // owned batch row
    const f32x4 bR = *(const f32x4*)(bias + cc0);
    const f32x4 bU = *(const f32x4*)(bias + 512 + cc0);
    const f32x4 bC = *(const f32x4*)(bias + 1024 + cc0);

    float h_own[4];
#pragma unroll
    for (int jj = 0; jj < 4; ++jj)
        h_own[jj] = h0[(size_t)b * 1024 + d * 512 + cc0 + jj];

    const int cswz = (lr & 7) << 4;
    const size_t rowbase = ((size_t)d * 64 + b) * 128;  // ulong units, [d][b][k/4]
    const size_t pubidx  = rowbase + w * 4 + lg;        // this thread's publish slot

    auto stage_xgs = [&](int buf, int ss) {
        const unsigned short* base = xg + (size_t)ss * (64 * 3072) + d * 1536 + w * 16;
        for (int ch = t; ch < 384; ch += 256) {
            int e0 = ch << 3;
            int g = e0 >> 10, bb = (e0 >> 4) & 63, hf = (e0 >> 3) & 1;
            short8 v = *(const short8*)(base + (size_t)bb * 3072 + g * 512 + hf * 8);
            *(short8*)(&xgs[buf][g * 1024 + bb * 16 + hf * 8]) = v;
        }
    };

    stage_xgs(0, d ? 511 : 0);
    __syncthreads();   // Wl + xgs[0] visible

    int bar = 0, cur = 0;
    for (int step = 0; step < 512; ++step) {
        const int s = d ? (511 - step) : step;
        const unsigned short* xc = xgs[cur];

        // ---- phase 1: pre-issue h fragment loads (sc1, register-direct) ----
        short8 hfr[16];
#pragma unroll
        for (int ks = 0; ks < 16; ++ks) {
            size_t idx = rowbase + ks * 8 + lg * 2;
            ulongx2 v;
            v.x = __hip_atomic_load(h64 + idx, __ATOMIC_RELAXED, __HIP_MEMORY_SCOPE_AGENT);
            v.y = __hip_atomic_load(h64 + idx + 1, __ATOMIC_RELAXED, __HIP_MEMORY_SCOPE_AGENT);
            hfr[ks] = __builtin_bit_cast(short8, v);
        }
        f32x4 accR = {0.f, 0.f, 0.f, 0.f}, accU = {0.f, 0.f, 0.f, 0.f};
#pragma unroll
        for (int ks = 0; ks < 16; ++ks) {
            int koff = (ks * 32 + lg * 8) * 2;
            short8 w0 = *(const short8*)((const char*)Wl + (((lr << 10) + koff) ^ cswz));
            short8 w1 = *(const short8*)((const char*)Wl + ((16384 + (lr << 10) + koff) ^ cswz));
            accR = __builtin_amdgcn_mfma_f32_16x16x32_bf16(w0, hfr[ks], accR, 0, 0, 0);
            accU = __builtin_amdgcn_mfma_f32_16x16x32_bf16(w1, hfr[ks], accU, 0, 0, 0);
        }
        float uu[4];
        unsigned long long rhp = 0;
#pragma unroll
        for (int jj = 0; jj < 4; ++jj) {
            float xr = bf2f(xc[b * 16 + lg * 4 + jj]);
            float xu = bf2f(xc[1024 + b * 16 + lg * 4 + jj]);
            float pr = accR[jj] + xr + bR[jj];
            float pu = accU[jj] + xu + bU[jj];
            float r = 1.f / (1.f + __expf(-pr));
            uu[jj] = 1.f / (1.f + __expf(-pu));
            rhp |= (unsigned long long)f2bf(r * h_own[jj]) << (16 * jj);
        }
        __hip_atomic_store(rh64 + pubidx, rhp, __ATOMIC_RELAXED, __HIP_MEMORY_SCOPE_AGENT);

        // ---- barrier 1 (rh ready); xg prefetch under it; NO cache ops ----
        ++bar;
        __syncthreads();   // compiler emits vmcnt(0): sc1 stores drained to LLC
        if (t == 0)
            __hip_atomic_store(&flags[blk], bar, __ATOMIC_RELAXED, __HIP_MEMORY_SCOPE_AGENT);
        if (step + 1 < 512) stage_xgs(cur ^ 1, d ? (510 - step) : (step + 1));
        if (t < 32) {
            while (__hip_atomic_load(&flags[d * 32 + t], __ATOMIC_RELAXED,
                                     __HIP_MEMORY_SCOPE_AGENT) < bar)
                __builtin_amdgcn_s_sleep(1);
        }
        __builtin_amdgcn_fence(__ATOMIC_ACQUIRE, "workgroup");
        __syncthreads();

        // ---- phase 2: pre-issue rh fragment loads ----
        short8 rfr[16];
#pragma unroll
        for (int ks = 0; ks < 16; ++ks) {
            size_t idx = rowbase + ks * 8 + lg * 2;
            ulongx2 v;
            v.x = __hip_atomic_load(rh64 + idx, __ATOMIC_RELAXED, __HIP_MEMORY_SCOPE_AGENT);
            v.y = __hip_atomic_load(rh64 + idx + 1, __ATOMIC_RELAXED, __HIP_MEMORY_SCOPE_AGENT);
            rfr[ks] = __builtin_bit_cast(short8, v);
        }
        f32x4 accC = {0.f, 0.f, 0.f, 0.f};
#pragma unroll
        for (int ks = 0; ks < 16; ++ks) {
            int koff = (ks * 32 + lg * 8) * 2;
            short8 w2 = *(const short8*)((const char*)Wl + ((32768 + (lr << 10) + koff) ^ cswz));
            accC = __builtin_amdgcn_mfma_f32_16x16x32_bf16(w2, rfr[ks], accC, 0, 0, 0);
        }
        f32x4 ov;
        unsigned long long hp = 0;
#pragma unroll
        for (int jj = 0; jj < 4; ++jj) {
            float xv = bf2f(xc[2048 + b * 16 + lg * 4 + jj]);
            float pc = accC[jj] + xv + bC[jj];
            float e = __expf(-2.f * pc);
            float c = 2.f / (1.f + e) - 1.f;                 // tanh
            float hn = uu[jj] * h_own[jj] + (1.f - uu[jj]) * c;
            h_own[jj] = hn;
            ov[jj] = hn;
            hp |= (unsigned long long)f2bf(hn) << (16 * jj);
        }
        *(f32x4*)(out + ((size_t)s * 64 + b) * 1024 + d * 512 + cc0) = ov;
        __hip_atomic_store(h64 + pubidx, hp, __ATOMIC_RELAXED, __HIP_MEMORY_SCOPE_AGENT);
        if (step == 511) {
            *(f32x4*)(out + (size_t)33554432 + (size_t)b * 1024 + d * 512 + cc0) = ov;
            break;   // no barrier needed after last step
        }

        // ---- barrier 2 (h ready) ----
        ++bar;
        __syncthreads();
        if (t == 0)
            __hip_atomic_store(&flags[blk], bar, __ATOMIC_RELAXED, __HIP_MEMORY_SCOPE_AGENT);
        if (t < 32) {
            while (__hip_atomic_load(&flags[d * 32 + t], __ATOMIC_RELAXED,
                                     __HIP_MEMORY_SCOPE_AGENT) < bar)
                __builtin_amdgcn_s_sleep(1);
        }
        __builtin_amdgcn_fence(__ATOMIC_ACQUIRE, "workgroup");
        __syncthreads();
        cur ^= 1;
    }
}

// ---------------- launcher ----------------

extern "C" void kernel_launch(void* const* d_in, const int* in_sizes, int n_in,
                              void* d_out, int out_size, void* d_ws, size_t ws_size,
                              hipStream_t stream) {
    const float* x   = (const float*)d_in[0];
    const float* h0  = (const float*)d_in[1];
    const float* Wxf = (const float*)d_in[2];
    const float* Whf = (const float*)d_in[3];
    const float* bf_ = (const float*)d_in[4];
    const float* Wxb = (const float*)d_in[5];
    const float* Whb = (const float*)d_in[6];
    const float* bb_ = (const float*)d_in[7];
    float* out = (float*)d_out;

    char* ws = (char*)d_ws;
    size_t off = 0;
    auto take = [&](size_t bytes) {
        char* p = ws + off;
        off += (bytes + 255) & ~(size_t)255;
        return p;
    };
    unsigned short* xb   = (unsigned short*)take((size_t)33554432 * 2);          // x bf16
    unsigned short* wt   = (unsigned short*)take((size_t)3072 * 1024 * 2);       // Wx^T bf16
    unsigned short* xgp  = (unsigned short*)take((size_t)32768 * 3072 * 2);      // gates bf16
    unsigned short* whsl = (unsigned short*)take((size_t)2 * 32 * 3 * 16 * 512 * 2);
    unsigned long long* h64  = (unsigned long long*)take((size_t)2 * 64 * 512 * 2);
    unsigned long long* rh64 = (unsigned long long*)take((size_t)2 * 64 * 512 * 2);
    int* flags           = (int*)take((size_t)1024 * 4);

    if (off > ws_size) return;

    hipLaunchKernelGGL(k_cvt_x,    dim3(16384),   dim3(256), 0, stream, x, xb);
    hipLaunchKernelGGL(k_cvt_w,    dim3(1536),    dim3(256), 0, stream, Wxf, Wxb, wt);
    hipLaunchKernelGGL(k_cvt_whsl, dim3(768),     dim3(256), 0, stream, Whf, Whb, whsl);
    hipLaunchKernelGGL(k_init,     dim3(256),     dim3(256), 0, stream, h0,
                       (unsigned short*)h64, flags);
    hipLaunchKernelGGL(k_gemm,     dim3(24, 256), dim3(256), 0, stream, xb, wt, xgp);
    hipLaunchKernelGGL(k_rec,      dim3(64),      dim3(256), 0, stream, xgp, whsl, h0,
                       bf_, bb_, h64, rh64, flags, out);
}